// Round 4
// baseline (162.026 us; speedup 1.0000x reference)
//
#include <hip/hip_runtime.h>

#define NSEQ 4096
#define EDIM 1024

// ws layout (floats)
#define OFF_PBX 0u        // partial Bx [2 halves][64 chains][4096] = 2 MB
#define OFF_HT  524288u   // h transposed [4][4096][16] = 1 MB

__device__ __forceinline__ void fma4(float4& a, float xv, const float4& b) {
    a.x = fmaf(xv, b.x, a.x);
    a.y = fmaf(xv, b.y, a.y);
    a.z = fmaf(xv, b.z, a.z);
    a.w = fmaf(xv, b.w, a.w);
}

// ---------------------------------------------------------------------------
// k1: partial Bx = x @ B_in over one e-half (512 e). Split-K across 2 blocks
// per 64-row group -> 512 blocks x 256 threads = 2 blocks/CU, 8 waves/CU.
// lane = row; wave's e-slice is WAVE-UNIFORM (B rows via s_load, SGPR
// operands). x staged via double-buffered LDS, pitch 132 (16B-aligned ->
// ds_write_b128 / ds_read_b128, conflict-light), 1 barrier per chunk.
// ---------------------------------------------------------------------------
__global__ __launch_bounds__(256, 2) void k1_bx(const float* __restrict__ x,
                                                const float* __restrict__ Bin,
                                                float* __restrict__ ws) {
    __shared__ float smem[2 * 64 * 132];   // two 33.8 KB stage buffers

    const int tid  = threadIdx.x;
    const int lane = tid & 63;                                  // row
    const int wu   = __builtin_amdgcn_readfirstlane(tid) >> 6;  // wave id
    const int r0   = (blockIdx.x >> 1) * 64;                    // row base
    const int eh   = blockIdx.x & 1;                            // e-half
    const int b    = r0 >> 12;
    const int n0   = r0 & 4095;

    const float4* xf4 = (const float4*)x;
    const float4* Bf4 = (const float4*)Bin;

    float acc[16];
#pragma unroll
    for (int s = 0; s < 16; s++) acc[s] = 0.f;

    // prefetch chunk 0: chunk = 64 rows x 128 e = 2048 float4; 8 per thread
    float4 pf[8];
#pragma unroll
    for (int k = 0; k < 8; k++) {
        int i = tid + 256 * k, row = i >> 5, c4 = i & 31;
        pf[k] = xf4[(size_t)(r0 + row) * 256 + eh * 128 + c4];
    }

    for (int c = 0; c < 4; ++c) {
        float* stg = &smem[(c & 1) * 8448];
#pragma unroll
        for (int k = 0; k < 8; k++) {
            int i = tid + 256 * k, row = i >> 5, c4 = i & 31;
            *(float4*)&stg[row * 132 + c4 * 4] = pf[k];
        }
        if (c < 3) {
#pragma unroll
            for (int k = 0; k < 8; k++) {
                int i = tid + 256 * k, row = i >> 5, c4 = i & 31;
                pf[k] = xf4[(size_t)(r0 + row) * 256 + eh * 128 + (c + 1) * 32 + c4];
            }
        }
        __syncthreads();   // staged chunk visible; prefetch c+1 in flight

        // wave wu covers e-locals [wu*32, +32), uniform -> B via s_load
#pragma unroll
        for (int j4 = 0; j4 < 8; j4++) {
            const float4 xq = *(const float4*)&stg[lane * 132 + wu * 32 + j4 * 4];
#pragma unroll
            for (int jj = 0; jj < 4; jj++) {
                const int e = eh * 512 + c * 128 + wu * 32 + j4 * 4 + jj; // uniform
                const float4 b0 = Bf4[e * 4 + 0];
                const float4 b1 = Bf4[e * 4 + 1];
                const float4 b2 = Bf4[e * 4 + 2];
                const float4 b3 = Bf4[e * 4 + 3];
                const float xv = (jj == 0) ? xq.x : (jj == 1) ? xq.y
                                : (jj == 2) ? xq.z : xq.w;
                acc[0]  = fmaf(xv, b0.x, acc[0]);  acc[1]  = fmaf(xv, b0.y, acc[1]);
                acc[2]  = fmaf(xv, b0.z, acc[2]);  acc[3]  = fmaf(xv, b0.w, acc[3]);
                acc[4]  = fmaf(xv, b1.x, acc[4]);  acc[5]  = fmaf(xv, b1.y, acc[5]);
                acc[6]  = fmaf(xv, b1.z, acc[6]);  acc[7]  = fmaf(xv, b1.w, acc[7]);
                acc[8]  = fmaf(xv, b2.x, acc[8]);  acc[9]  = fmaf(xv, b2.y, acc[9]);
                acc[10] = fmaf(xv, b2.z, acc[10]); acc[11] = fmaf(xv, b2.w, acc[11]);
                acc[12] = fmaf(xv, b3.x, acc[12]); acc[13] = fmaf(xv, b3.y, acc[13]);
                acc[14] = fmaf(xv, b3.z, acc[14]); acc[15] = fmaf(xv, b3.w, acc[15]);
            }
        }
        __syncthreads();   // all reads of this buffer done before re-write
    }

    // cross-wave reduction: red[4 waves][64 rows][17] aliases buffer 0
    {
        const int rb = (wu * 64 + lane) * 17;   // 17*lane -> conflict-free
#pragma unroll
        for (int s = 0; s < 16; s++) smem[rb + s] = acc[s];
    }
    __syncthreads();

#pragma unroll
    for (int q = 0; q < 4; q++) {
        const int o   = tid + 256 * q;
        const int s   = o >> 6;      // wave-uniform
        const int row = o & 63;
        const float v = smem[(0 * 64 + row) * 17 + s] + smem[(1 * 64 + row) * 17 + s] +
                        smem[(2 * 64 + row) * 17 + s] + smem[(3 * 64 + row) * 17 + s];
        ws[OFF_PBX + eh * 262144u + (size_t)(b * 16 + s) * NSEQ + n0 + row] = v;
    }
}

// ---------------------------------------------------------------------------
// k2: sum the two partial-Bx halves, softplus -> decay, full 4096-step scan.
// 64 blocks (1 per chain) x 256 threads; thread composes 16 steps; wave-level
// shuffle scan + single-LDS wave-total combine (1 barrier). Writes h in
// transposed layout ht[b][t][s] for k3's scalar loads.
// ---------------------------------------------------------------------------
__global__ __launch_bounds__(256) void k2_scan(const float* __restrict__ A,
                                               float* __restrict__ ws) {
    __shared__ float sP[4], sH[4];
    const int tid   = threadIdx.x;
    const int lane  = tid & 63;
    const int w     = tid >> 6;
    const int chain = blockIdx.x;
    const int bb    = chain >> 4, ss = chain & 15;

    const float4* P0 = (const float4*)(ws + OFF_PBX) + (size_t)chain * 1024;
    const float4* P1 = (const float4*)(ws + OFF_PBX + 262144u) + (size_t)chain * 1024;

    float bx[16], de[16];
    const float Ae = expf(A[ss]);
#pragma unroll
    for (int k = 0; k < 4; k++) {
        float4 a0 = P0[tid * 4 + k], a1 = P1[tid * 4 + k];
        float vv[4] = {a0.x + a1.x, a0.y + a1.y, a0.z + a1.z, a0.w + a1.w};
#pragma unroll
        for (int j = 0; j < 4; j++) {
            float v  = vv[j];
            float sp = fmaxf(v, 0.f) + log1pf(expf(-fabsf(v)));
            bx[k * 4 + j] = v;
            de[k * 4 + j] = expf(-Ae * sp);
        }
    }

    // compose 16 steps: (P, h)
    float P = 1.f, h = 0.f;
#pragma unroll
    for (int k = 0; k < 16; k++) { h = fmaf(h, de[k], bx[k]); P *= de[k]; }

    // wave-inclusive scan over 64 lanes
    float Pi = P, hi = h;
#pragma unroll
    for (int off = 1; off < 64; off <<= 1) {
        float Pp = __shfl_up(Pi, off, 64);
        float hp = __shfl_up(hi, off, 64);
        if (lane >= off) { hi = fmaf(hp, Pi, hi); Pi *= Pp; }
    }

    if (lane == 63) { sP[w] = Pi; sH[w] = hi; }
    __syncthreads();

    // prefix over preceding waves (<=3 serial combines, uniform per wave)
    float hw = 0.f;
    for (int q = 0; q < w; q++) hw = fmaf(hw, sP[q], sH[q]);

    // lane-exclusive within wave
    float Pe = __shfl_up(Pi, 1, 64);
    float he = __shfl_up(hi, 1, 64);
    if (lane == 0) { Pe = 1.f; he = 0.f; }
    float hr = fmaf(hw, Pe, he);   // global exclusive prefix h

    // expand 16 steps, store transposed ht[bb][t][ss]
    float* htp = ws + OFF_HT + ((size_t)bb * NSEQ + tid * 16) * 16 + ss;
#pragma unroll
    for (int k = 0; k < 16; k++) {
        hr = fmaf(hr, de[k], bx[k]);
        htp[k * 16] = hr;
    }
}

// ---------------------------------------------------------------------------
// k3: y[b,t,e] = sum_s h[b,t,s]*C[s,e] + x[b,t,e]*D[e].
// 1024 blocks x 256 threads. C columns in VGPRs, h via block-uniform scalar
// loads. D == 0 fast path skips the x read (slow path kept correct).
// ---------------------------------------------------------------------------
__global__ __launch_bounds__(256) void k3_out(const float* __restrict__ x,
                                              const float* __restrict__ C,
                                              const float* __restrict__ D,
                                              const float* __restrict__ ws,
                                              float* __restrict__ out) {
    const int tid = threadIdx.x;
    const int blk = blockIdx.x;
    const int tc  = blk & 255;
    const int b   = blk >> 8;
    const int t0  = tc * 16;

    const float4* C4 = (const float4*)C;  // [16][256] float4
    float4 creg[16];
#pragma unroll
    for (int s = 0; s < 16; s++) creg[s] = C4[s * 256 + tid];
    float4 dreg = ((const float4*)D)[tid];

    const bool needX = __any((dreg.x != 0.f) | (dreg.y != 0.f) |
                             (dreg.z != 0.f) | (dreg.w != 0.f));

    const float* hb = ws + OFF_HT + ((size_t)b * NSEQ + t0) * 16;  // 16x16 tile

    const float4* x4 = (const float4*)x;
    float4* o4 = (float4*)out;
    const size_t rowbase = ((size_t)b * NSEQ + t0) * 256;

    if (needX) {
#pragma unroll 4
        for (int tt = 0; tt < 16; tt++) {
            float4 xv = x4[rowbase + tt * 256 + tid];
            float4 y;
            y.x = xv.x * dreg.x; y.y = xv.y * dreg.y;
            y.z = xv.z * dreg.z; y.w = xv.w * dreg.w;
#pragma unroll
            for (int s = 0; s < 16; s++) fma4(y, hb[tt * 16 + s], creg[s]);
            o4[rowbase + tt * 256 + tid] = y;
        }
    } else {
#pragma unroll 4
        for (int tt = 0; tt < 16; tt++) {
            float4 y = make_float4(0.f, 0.f, 0.f, 0.f);
#pragma unroll
            for (int s = 0; s < 16; s++) fma4(y, hb[tt * 16 + s], creg[s]);
            o4[rowbase + tt * 256 + tid] = y;
        }
    }
}

extern "C" void kernel_launch(void* const* d_in, const int* in_sizes, int n_in,
                              void* d_out, int out_size, void* d_ws, size_t ws_size,
                              hipStream_t stream) {
    const float* x   = (const float*)d_in[0];
    const float* A   = (const float*)d_in[1];
    const float* Bin = (const float*)d_in[2];
    const float* C   = (const float*)d_in[3];
    const float* D   = (const float*)d_in[4];
    float* out = (float*)d_out;
    float* ws  = (float*)d_ws;

    hipLaunchKernelGGL(k1_bx,   dim3(512),  dim3(256), 0, stream, x, Bin, ws);
    hipLaunchKernelGGL(k2_scan, dim3(64),   dim3(256), 0, stream, A, ws);
    hipLaunchKernelGGL(k3_out,  dim3(1024), dim3(256), 0, stream, x, C, D, ws, out);
}

// Round 5
// 140.182 us; speedup vs baseline: 1.1558x; 1.1558x over previous
//
#include <hip/hip_runtime.h>

#define NSEQ 4096
#define EDIM 1024

// ws layout (floats)
#define OFF_PBX 0u          // partial Bx [4 quarters][64 chains][4096] = 4 MB
#define OFF_HT  1048576u    // h transposed [4][4096][16] = 1 MB

__device__ __forceinline__ void fma4(float4& a, float xv, const float4& b) {
    a.x = fmaf(xv, b.x, a.x);
    a.y = fmaf(xv, b.y, a.y);
    a.z = fmaf(xv, b.z, a.z);
    a.w = fmaf(xv, b.w, a.w);
}

// ---------------------------------------------------------------------------
// k1: partial Bx = x @ B_in over one e-quarter (256 e).
// 1024 blocks (256 row-groups x 4 quarters) x 256 threads -> 4 blocks/CU,
// 16 waves/CU. lane = row; wave's 16-e slice is WAVE-UNIFORM (B via s_load,
// SGPR operands into v_fma). x staged in double-buffered LDS chunks of
// 64 rows x 64 e, pitch 65 (stride == 1 mod 32: conflict-free b32 r/w).
// One barrier per chunk; prefetch of chunk c+1 overlaps compute of c.
// ---------------------------------------------------------------------------
__global__ __launch_bounds__(256, 4) void k1_bx(const float* __restrict__ x,
                                                const float* __restrict__ Bin,
                                                float* __restrict__ ws) {
    __shared__ float smem[2 * 64 * 65];    // 33.3 KB

    const int tid  = threadIdx.x;
    const int lane = tid & 63;                                  // row
    const int wu   = __builtin_amdgcn_readfirstlane(tid) >> 6;  // wave id
    const int q    = blockIdx.x & 3;                            // e-quarter
    const int r0   = (blockIdx.x >> 2) * 64;                    // row base
    const int b    = r0 >> 12;
    const int n0   = r0 & 4095;
    const int eq   = q * 256;

    const float4* xf4 = (const float4*)x;
    const float4* Bf4 = (const float4*)Bin;

    float acc[16];
#pragma unroll
    for (int s = 0; s < 16; s++) acc[s] = 0.f;

    // prefetch chunk 0: 64 rows x 64 e = 1024 float4; 4 per thread
    float4 pf[4];
#pragma unroll
    for (int k = 0; k < 4; k++) {
        int i = tid + 256 * k, row = i >> 4, cq = i & 15;
        pf[k] = xf4[(size_t)(r0 + row) * 256 + q * 64 + cq];
    }
    {   // stage chunk 0
        float* stg = smem;
#pragma unroll
        for (int k = 0; k < 4; k++) {
            int i = tid + 256 * k, row = i >> 4, cq = i & 15;
            float* p = &stg[row * 65 + cq * 4];
            p[0] = pf[k].x; p[1] = pf[k].y; p[2] = pf[k].z; p[3] = pf[k].w;
        }
    }
    __syncthreads();

    for (int c = 0; c < 4; ++c) {
        // prefetch chunk c+1 (global; lands in regs)
        if (c < 3) {
#pragma unroll
            for (int k = 0; k < 4; k++) {
                int i = tid + 256 * k, row = i >> 4, cq = i & 15;
                pf[k] = xf4[(size_t)(r0 + row) * 256 + q * 64 + (c + 1) * 16 + cq];
            }
        }

        // compute chunk c from buf[c&1]; wave covers e-locals [wu*16, +16)
        const float* stg = &smem[(c & 1) * 4160];
#pragma unroll
        for (int j = 0; j < 16; ++j) {
            const int el = wu * 16 + j;                 // wave-uniform
            const int e  = eq + c * 64 + el;            // wave-uniform
            const float4 b0 = Bf4[e * 4 + 0];
            const float4 b1 = Bf4[e * 4 + 1];
            const float4 b2 = Bf4[e * 4 + 2];
            const float4 b3 = Bf4[e * 4 + 3];
            const float xv = stg[lane * 65 + el];       // conflict-free b32
            acc[0]  = fmaf(xv, b0.x, acc[0]);  acc[1]  = fmaf(xv, b0.y, acc[1]);
            acc[2]  = fmaf(xv, b0.z, acc[2]);  acc[3]  = fmaf(xv, b0.w, acc[3]);
            acc[4]  = fmaf(xv, b1.x, acc[4]);  acc[5]  = fmaf(xv, b1.y, acc[5]);
            acc[6]  = fmaf(xv, b1.z, acc[6]);  acc[7]  = fmaf(xv, b1.w, acc[7]);
            acc[8]  = fmaf(xv, b2.x, acc[8]);  acc[9]  = fmaf(xv, b2.y, acc[9]);
            acc[10] = fmaf(xv, b2.z, acc[10]); acc[11] = fmaf(xv, b2.w, acc[11]);
            acc[12] = fmaf(xv, b3.x, acc[12]); acc[13] = fmaf(xv, b3.y, acc[13]);
            acc[14] = fmaf(xv, b3.z, acc[14]); acc[15] = fmaf(xv, b3.w, acc[15]);
        }

        // stage chunk c+1 into the other buffer (read by compute(c-1), which
        // finished before the barrier at the end of the previous iteration)
        if (c < 3) {
            float* dst = &smem[((c + 1) & 1) * 4160];
#pragma unroll
            for (int k = 0; k < 4; k++) {
                int i = tid + 256 * k, row = i >> 4, cq = i & 15;
                float* p = &dst[row * 65 + cq * 4];
                p[0] = pf[k].x; p[1] = pf[k].y; p[2] = pf[k].z; p[3] = pf[k].w;
            }
        }
        __syncthreads();
    }

    // cross-wave reduction: red[4 waves][64 rows][17] aliases the buffers
    {
        const int rb = (wu * 64 + lane) * 17;
#pragma unroll
        for (int s = 0; s < 16; s++) smem[rb + s] = acc[s];
    }
    __syncthreads();

#pragma unroll
    for (int p = 0; p < 4; p++) {
        const int o   = tid + 256 * p;
        const int s   = o >> 6;      // wave-uniform
        const int row = o & 63;
        const float v = smem[(0 * 64 + row) * 17 + s] + smem[(1 * 64 + row) * 17 + s] +
                        smem[(2 * 64 + row) * 17 + s] + smem[(3 * 64 + row) * 17 + s];
        ws[OFF_PBX + (size_t)q * 262144u + (size_t)(b * 16 + s) * NSEQ + n0 + row] = v;
    }
}

// ---------------------------------------------------------------------------
// k2: sum 4 partial-Bx quarters, softplus -> decay, full 4096-step scan.
// 64 blocks (1 per chain) x 256 threads; thread composes 16 steps; wave
// shuffle scan + 4-entry LDS combine (1 barrier). Writes h transposed
// ht[b][t][s] for k3's block-uniform scalar loads.
// ---------------------------------------------------------------------------
__global__ __launch_bounds__(256) void k2_scan(const float* __restrict__ A,
                                               float* __restrict__ ws) {
    __shared__ float sP[4], sH[4];
    const int tid   = threadIdx.x;
    const int lane  = tid & 63;
    const int w     = tid >> 6;
    const int chain = blockIdx.x;
    const int bb    = chain >> 4, ss = chain & 15;

    float bx[16], de[16];
    const float Ae = expf(A[ss]);
#pragma unroll
    for (int k = 0; k < 4; k++) {
        float4 v4 = make_float4(0.f, 0.f, 0.f, 0.f);
#pragma unroll
        for (int q = 0; q < 4; q++) {
            const float4* Pq = (const float4*)(ws + OFF_PBX + (size_t)q * 262144u +
                                               (size_t)chain * NSEQ);
            float4 a = Pq[tid * 4 + k];
            v4.x += a.x; v4.y += a.y; v4.z += a.z; v4.w += a.w;
        }
        float vv[4] = {v4.x, v4.y, v4.z, v4.w};
#pragma unroll
        for (int j = 0; j < 4; j++) {
            float v  = vv[j];
            float sp = fmaxf(v, 0.f) + log1pf(expf(-fabsf(v)));
            bx[k * 4 + j] = v;
            de[k * 4 + j] = expf(-Ae * sp);
        }
    }

    // compose 16 steps: (P, h)
    float P = 1.f, h = 0.f;
#pragma unroll
    for (int k = 0; k < 16; k++) { h = fmaf(h, de[k], bx[k]); P *= de[k]; }

    // wave-inclusive scan over 64 lanes
    float Pi = P, hi = h;
#pragma unroll
    for (int off = 1; off < 64; off <<= 1) {
        float Pp = __shfl_up(Pi, off, 64);
        float hp = __shfl_up(hi, off, 64);
        if (lane >= off) { hi = fmaf(hp, Pi, hi); Pi *= Pp; }
    }

    if (lane == 63) { sP[w] = Pi; sH[w] = hi; }
    __syncthreads();

    float hw = 0.f;
    for (int qq = 0; qq < w; qq++) hw = fmaf(hw, sP[qq], sH[qq]);

    float Pe = __shfl_up(Pi, 1, 64);
    float he = __shfl_up(hi, 1, 64);
    if (lane == 0) { Pe = 1.f; he = 0.f; }
    float hr = fmaf(hw, Pe, he);   // global exclusive prefix h

    float* htp = ws + OFF_HT + ((size_t)bb * NSEQ + tid * 16) * 16 + ss;
#pragma unroll
    for (int k = 0; k < 16; k++) {
        hr = fmaf(hr, de[k], bx[k]);
        htp[k * 16] = hr;
    }
}

// ---------------------------------------------------------------------------
// k3: y[b,t,e] = sum_s h[b,t,s]*C[s,e] + x[b,t,e]*D[e].
// 1024 blocks x 256 threads. C columns in VGPRs, h via block-uniform scalar
// loads. D == 0 fast path skips the x read (slow path kept correct).
// ---------------------------------------------------------------------------
__global__ __launch_bounds__(256) void k3_out(const float* __restrict__ x,
                                              const float* __restrict__ C,
                                              const float* __restrict__ D,
                                              const float* __restrict__ ws,
                                              float* __restrict__ out) {
    const int tid = threadIdx.x;
    const int blk = blockIdx.x;
    const int tc  = blk & 255;
    const int b   = blk >> 8;
    const int t0  = tc * 16;

    const float4* C4 = (const float4*)C;  // [16][256] float4
    float4 creg[16];
#pragma unroll
    for (int s = 0; s < 16; s++) creg[s] = C4[s * 256 + tid];
    float4 dreg = ((const float4*)D)[tid];

    const bool needX = __any((dreg.x != 0.f) | (dreg.y != 0.f) |
                             (dreg.z != 0.f) | (dreg.w != 0.f));

    const float* hb = ws + OFF_HT + ((size_t)b * NSEQ + t0) * 16;  // 16x16 tile

    const float4* x4 = (const float4*)x;
    float4* o4 = (float4*)out;
    const size_t rowbase = ((size_t)b * NSEQ + t0) * 256;

    if (needX) {
#pragma unroll 4
        for (int tt = 0; tt < 16; tt++) {
            float4 xv = x4[rowbase + tt * 256 + tid];
            float4 y;
            y.x = xv.x * dreg.x; y.y = xv.y * dreg.y;
            y.z = xv.z * dreg.z; y.w = xv.w * dreg.w;
#pragma unroll
            for (int s = 0; s < 16; s++) fma4(y, hb[tt * 16 + s], creg[s]);
            o4[rowbase + tt * 256 + tid] = y;
        }
    } else {
#pragma unroll 4
        for (int tt = 0; tt < 16; tt++) {
            float4 y = make_float4(0.f, 0.f, 0.f, 0.f);
#pragma unroll
            for (int s = 0; s < 16; s++) fma4(y, hb[tt * 16 + s], creg[s]);
            o4[rowbase + tt * 256 + tid] = y;
        }
    }
}

extern "C" void kernel_launch(void* const* d_in, const int* in_sizes, int n_in,
                              void* d_out, int out_size, void* d_ws, size_t ws_size,
                              hipStream_t stream) {
    const float* x   = (const float*)d_in[0];
    const float* A   = (const float*)d_in[1];
    const float* Bin = (const float*)d_in[2];
    const float* C   = (const float*)d_in[3];
    const float* D   = (const float*)d_in[4];
    float* out = (float*)d_out;
    float* ws  = (float*)d_ws;

    hipLaunchKernelGGL(k1_bx,   dim3(1024), dim3(256), 0, stream, x, Bin, ws);
    hipLaunchKernelGGL(k2_scan, dim3(64),   dim3(256), 0, stream, A, ws);
    hipLaunchKernelGGL(k3_out,  dim3(1024), dim3(256), 0, stream, x, C, D, ws, out);
}